// Round 12
// baseline (296.666 us; speedup 1.0000x reference)
//
#include <hip/hip_runtime.h>
#include <math.h>

#define EPSV 1e-5f
#define IS3  0.57735026918962576f   // 1/sqrt(3)
#define PNRM 0.125f                 // 1/sqrt(2*32)

typedef __attribute__((ext_vector_type(8)))  short  short8;
typedef __attribute__((ext_vector_type(16))) float  floatx16;

static __device__ inline unsigned short f2bf(float f) {
    unsigned int u = __float_as_uint(f);
    return (unsigned short)((u + 0x7fff + ((u >> 16) & 1)) >> 16);  // RNE
}
static __device__ inline float bflo(unsigned int u) { return __uint_as_float(u << 16); }
static __device__ inline float bfhi(unsigned int u) { return __uint_as_float(u & 0xffff0000u); }

// ---- K0: coalesced LDS-transpose f32 -> bf16 swizzled col-tiles, + deg count.
// blocks 0..127: W2 col-tiles; 128..131: W1 col-tiles; 132+: deg atomics
// tile layout (shorts): tile*4096 + kc*256 + (c&31)*8 + k7
__global__ __launch_bounds__(256) void k0_tile(const float* __restrict__ W2,
                                               const float* __restrict__ W1,
                                               unsigned short* __restrict__ W2T,
                                               unsigned short* __restrict__ W1T,
                                               const int* __restrict__ ei,
                                               int* __restrict__ deg, int E) {
    const int bx = blockIdx.x, tid = threadIdx.x;
    if (bx >= 132) {
        int e = (bx - 132) * 256 + tid;
        if (e < E) atomicAdd(&deg[ei[e]], 1);
        return;
    }
    __shared__ float tile[128 * 33];
    const float* src;
    unsigned short* dst;
    int nc, tb;
    if (bx < 128) { src = W2; dst = W2T; nc = 4096; tb = bx; }
    else          { src = W1; dst = W1T; nc = 128;  tb = bx - 128; }
    const int c0 = tb * 32;
#pragma unroll
    for (int r = 0; r < 16; ++r) {
        int lin = r * 256 + tid;
        int k = lin >> 5, c = lin & 31;
        tile[k * 33 + c] = src[(size_t)k * nc + c0 + c];
    }
    __syncthreads();
#pragma unroll
    for (int r = 0; r < 2; ++r) {
        int g = r * 256 + tid;          // 0..511
        int kc = g >> 5, c = g & 31;
        short8 v;
#pragma unroll
        for (int j = 0; j < 8; ++j)
            v[j] = (short)f2bf(tile[(kc * 8 + j) * 33 + c]);
        *(short8*)(dst + (size_t)tb * 4096 + kc * 256 + c * 8) = v;
    }
}

// ---- K1: h = relu(ea @ W1 + b1) via MFMA 32x32x16.
// THIS REV (k2's own pattern applied to k1): NO LDS staging of W1T --
// B-fragments stream global->VGPR from the L2-resident 32KB W1T, exactly
// like k2's LOADB. No GLD16, no vmcnt drain, no __syncthreads: k1 is
// barrier-free. Blocks shrink to ONE WAVE (64 thr, 32 edges): 1875 blocks
// ~ 7.3/CU (vs 1.8) for latency hiding. Per-wave work unchanged vs R9
// (4 jt x 8 MFMA). Last block: 64-lane shfl-scan deg->rowptr.
// h layout unchanged: group g=e/32: g*4096 + (k>>3)*256 + (e&31)*8 + (k&7).
__global__ __launch_bounds__(64) void k1_fc(const float* __restrict__ ea,
                                            const unsigned short* __restrict__ W1T,
                                            const float* __restrict__ b1,
                                            unsigned short* __restrict__ hsw,
                                            const int* __restrict__ deg,
                                            int* __restrict__ rowptr,
                                            int N, int E) {
    const int lane = threadIdx.x & 63;
    const int half = lane >> 5, col = lane & 31;
    const int nfc = (E + 31) / 32;

    if (blockIdx.x >= nfc) {
        // exclusive prefix sum deg -> rowptr, single wave via shfl
        const int chunk = (N + 63) / 64;
        const int base = lane * chunk;
        int s = 0;
        for (int i = 0; i < chunk; ++i) {
            int n = base + i;
            if (n < N) s += deg[n];
        }
        int inc = s;
#pragma unroll
        for (int off = 1; off < 64; off <<= 1) {
            int t = __shfl_up(inc, off);
            if (lane >= off) inc += t;
        }
        int prefix = inc - s;           // exclusive
        for (int i = 0; i < chunk; ++i) {
            int n = base + i;
            if (n < N) { rowptr[n] = prefix; prefix += deg[n]; }
        }
        if (lane == 63) rowptr[N] = inc;
        return;
    }

    __shared__ __align__(16) unsigned short myb[1056];   // 2.1 KB wave bounce
    const int e0 = blockIdx.x * 32;

    int e = e0 + col; if (e >= E) e = E - 1;
    short8 afr[8];
#pragma unroll
    for (int c = 0; c < 8; ++c) {
        const float4* p = (const float4*)(ea + (size_t)e * 128 + c * 16 + half * 8);
        float4 f0 = p[0], f1 = p[1];
        short8 v;
        v[0] = (short)f2bf(f0.x); v[1] = (short)f2bf(f0.y);
        v[2] = (short)f2bf(f0.z); v[3] = (short)f2bf(f0.w);
        v[4] = (short)f2bf(f1.x); v[5] = (short)f2bf(f1.y);
        v[6] = (short)f2bf(f1.z); v[7] = (short)f2bf(f1.w);
        afr[c] = v;
    }

    const int gg = blockIdx.x;
#pragma unroll
    for (int jt = 0; jt < 4; ++jt) {
        floatx16 d = {0,0,0,0,0,0,0,0,0,0,0,0,0,0,0,0};
#pragma unroll
        for (int c = 0; c < 8; ++c) {
            short8 bf = *(const short8*)((const char*)W1T + jt * 8192 + (2 * c + half) * 512 + col * 16);
            d = __builtin_amdgcn_mfma_f32_32x32x16_bf16(afr[c], bf, d, 0, 0, 0);
        }
        float b1v = b1[jt * 32 + col];
#pragma unroll
        for (int reg = 0; reg < 16; ++reg) {
            int r = (reg & 3) + 8 * (reg >> 2) + 4 * half;
            float v = d[reg] + b1v;
            v = v > 0.f ? v : 0.f;
            myb[(col >> 3) * 264 + r * 8 + (col & 7)] = f2bf(v);
        }
#pragma unroll
        for (int s = 0; s < 2; ++s) {
            short8 v = *(const short8*)&myb[(s * 2 + (lane >> 5)) * 264 + (lane & 31) * 8];
            *(short8*)(hsw + (size_t)gg * 4096 + jt * 1024 + s * 512 + lane * 8) = v;
        }
    }
}

// ---- K2: MFMA 32x32x16 GEMM (h @ W2) fused with TP contraction.
// EXACT R9 kernel (verified 112us): barrier-free hot loop, posbuf CSR slots,
// CSR-ordered tp row stores. DO NOT TOUCH.
__global__ __launch_bounds__(256, 2) void k2_mfma(const unsigned short* __restrict__ hsw,
                                                  const unsigned short* __restrict__ W2T,
                                                  const float* __restrict__ b2,
                                                  const float* __restrict__ na,
                                                  const int* __restrict__ ei,
                                                  const float* __restrict__ sh,
                                                  const int* __restrict__ rowptr,
                                                  int* __restrict__ cursor,
                                                  float* __restrict__ tp, int E) {
    __shared__ __align__(16) char smem[32768];
    __shared__ int posbuf[64];                     // edge -> CSR slot (this block)
    unsigned short* Ctb = (unsigned short*)smem;   // 6 x 4 KB coef tables
    float* red = (float*)smem;                     // 32 KB epilogue alias

    const int tid = threadIdx.x, lane = tid & 63, wv = tid >> 6;
    const int half = lane >> 5, col = lane & 31;
    const int ust = wv >> 1, esub = wv & 1;
    const int e0 = blockIdx.x * 64;

    // merged k_fill: claim CSR slots for this block's edges (no elist store)
    if (tid < 64) {
        int e = e0 + tid;
        if (e < E) {
            int s = ei[e];
            posbuf[tid] = rowptr[s] + atomicAdd(&cursor[s], 1);
        }
    }

    // coef tables (bf16), [u][el], pre-scaled by PNRM / PNRM*IS3 / s0
    for (int idx = tid; idx < 2048; idx += 256) {
        int el = idx & 63, u = idx >> 6;
        int e = e0 + el; int ec = e < E ? e : E - 1;
        int dn = ei[E + ec];
        const float* nar = na + (size_t)dn * 128;
        float x0  = nar[u];
        float x10 = nar[32 + u * 3], x11 = nar[33 + u * 3], x12 = nar[34 + u * 3];
        const float* shr = sh + (size_t)ec * 4;
        float s0 = shr[0], s1 = shr[1], s2 = shr[2], s3 = shr[3];
        int o = u * 64 + el;
        Ctb[0 * 2048 + o] = f2bf(PNRM * x0 * s0);
        Ctb[1 * 2048 + o] = f2bf(PNRM * IS3 * x0);
        Ctb[2 * 2048 + o] = f2bf(PNRM * IS3 * s0 * x10);
        Ctb[3 * 2048 + o] = f2bf(PNRM * IS3 * s0 * x11);
        Ctb[4 * 2048 + o] = f2bf(PNRM * IS3 * s0 * x12);
        Ctb[5 * 2048 + o] = f2bf(PNRM * IS3 * (x10 * s1 + x11 * s2 + x12 * s3));
    }

    // A fragments direct from swizzled h (coalesced 512B/half-wave)
    const int gg = blockIdx.x * 2 + esub;
    short8 afr[8];
#pragma unroll
    for (int c = 0; c < 8; ++c)
        afr[c] = *(const short8*)(hsw + (size_t)gg * 4096 + (2 * c + half) * 256 + col * 8);

    __syncthreads();

    float acc0[16] = {}, accB[16] = {}, accC0[16] = {}, accC1[16] = {}, accC2[16] = {};
    const int elb0 = esub * 32 + half * 4;
    const unsigned short* bbase = W2T + half * 256 + col * 8;

#define LOADB(p, br, b2r) do {                                         \
        int _ct = 2 * (p) + ust;                                       \
        const unsigned short* _bp = bbase + (size_t)_ct * 4096;        \
        _Pragma("unroll")                                              \
        for (int _c = 0; _c < 8; ++_c)                                 \
            (br)[_c] = *(const short8*)(_bp + _c * 512);               \
        (b2r) = b2[_ct * 32 + col];                                    \
    } while (0)

#define COMPUTE(p, br, b2v) do {                                                              \
        const int _ct = 2 * (p) + ust;                                                        \
        const int _b = _ct >> 5, _u = _ct & 31;                                               \
        floatx16 d = {0,0,0,0,0,0,0,0,0,0,0,0,0,0,0,0};                                       \
        _Pragma("unroll")                                                                     \
        for (int _c = 0; _c < 8; ++_c)                                                        \
            d = __builtin_amdgcn_mfma_f32_32x32x16_bf16(afr[_c], (br)[_c], d, 0, 0, 0);       \
        if (_b == 0 || _b == 3) {                                                             \
            const unsigned short* tb = Ctb + (_b == 0 ? 0 : 5) * 2048;                        \
            _Pragma("unroll")                                                                 \
            for (int q = 0; q < 4; ++q) {                                                     \
                uint2 cv = *(const uint2*)&tb[_u * 64 + elb0 + q * 8];                        \
                acc0[q * 4 + 0] += bflo(cv.x) * (d[q * 4 + 0] + (b2v));                       \
                acc0[q * 4 + 1] += bfhi(cv.x) * (d[q * 4 + 1] + (b2v));                       \
                acc0[q * 4 + 2] += bflo(cv.y) * (d[q * 4 + 2] + (b2v));                       \
                acc0[q * 4 + 3] += bfhi(cv.y) * (d[q * 4 + 3] + (b2v));                       \
            }                                                                                 \
        } else if (_b == 1) {                                                                 \
            _Pragma("unroll")                                                                 \
            for (int q = 0; q < 4; ++q) {                                                     \
                uint2 cv = *(const uint2*)&Ctb[1 * 2048 + _u * 64 + elb0 + q * 8];            \
                accB[q * 4 + 0] += bflo(cv.x) * (d[q * 4 + 0] + (b2v));                       \
                accB[q * 4 + 1] += bfhi(cv.x) * (d[q * 4 + 1] + (b2v));                       \
                accB[q * 4 + 2] += bflo(cv.y) * (d[q * 4 + 2] + (b2v));                       \
                accB[q * 4 + 3] += bfhi(cv.y) * (d[q * 4 + 3] + (b2v));                       \
            }                                                                                 \
        } else {                                                                              \
            _Pragma("unroll")                                                                 \
            for (int q = 0; q < 4; ++q) {                                                     \
                uint2 cu0 = *(const uint2*)&Ctb[2 * 2048 + _u * 64 + elb0 + q * 8];           \
                uint2 cu1 = *(const uint2*)&Ctb[3 * 2048 + _u * 64 + elb0 + q * 8];           \
                uint2 cu2 = *(const uint2*)&Ctb[4 * 2048 + _u * 64 + elb0 + q * 8];           \
                float f0[4] = {bflo(cu0.x), bfhi(cu0.x), bflo(cu0.y), bfhi(cu0.y)};           \
                float f1[4] = {bflo(cu1.x), bfhi(cu1.x), bflo(cu1.y), bfhi(cu1.y)};           \
                float f2[4] = {bflo(cu2.x), bfhi(cu2.x), bflo(cu2.y), bfhi(cu2.y)};           \
                _Pragma("unroll")                                                             \
                for (int rr = 0; rr < 4; ++rr) {                                              \
                    float v = d[q * 4 + rr] + (b2v);                                          \
                    accC0[q * 4 + rr] += f0[rr] * v;                                          \
                    accC1[q * 4 + rr] += f1[rr] * v;                                          \
                    accC2[q * 4 + rr] += f2[rr] * v;                                          \
                }                                                                             \
            }                                                                                 \
        }                                                                                     \
    } while (0)

    short8 bA[8], bB[8], bC[8];
    float b2A, b2B, b2C;
    LOADB(0, bA, b2A); LOADB(1, bB, b2B); LOADB(2, bC, b2C);
    for (int p = 0; p < 60; p += 3) {
        COMPUTE(p,     bA, b2A); LOADB(p + 3, bA, b2A);
        COMPUTE(p + 1, bB, b2B); LOADB(p + 4, bB, b2B);
        COMPUTE(p + 2, bC, b2C); LOADB(p + 5, bC, b2C);
    }
    COMPUTE(60, bA, b2A); LOADB(63, bA, b2A);
    COMPUTE(61, bB, b2B);
    COMPUTE(62, bC, b2C);
    COMPUTE(63, bA, b2A);
#undef LOADB
#undef COMPUTE

    // epilogue: combine the two u-streams via LDS (red aliases Ctb)
    __syncthreads();
    if (ust == 1) {
#pragma unroll
        for (int q = 0; q < 4; ++q) {
#pragma unroll
            for (int rr = 0; rr < 4; ++rr) {
                int reg = q * 4 + rr;
                int el = esub * 32 + q * 8 + half * 4 + rr;
                int e = e0 + el; int ec = e < E ? e : E - 1;
                float4 sv = *(const float4*)(sh + (size_t)ec * 4);
                red[(((esub * 4 + 0) * 16 + reg) << 6) + lane] = acc0[reg];
                red[(((esub * 4 + 1) * 16 + reg) << 6) + lane] = sv.y * accB[reg] + accC0[reg];
                red[(((esub * 4 + 2) * 16 + reg) << 6) + lane] = sv.z * accB[reg] + accC1[reg];
                red[(((esub * 4 + 3) * 16 + reg) << 6) + lane] = sv.w * accB[reg] + accC2[reg];
            }
        }
    }
    __syncthreads();
    if (ust == 0) {
#pragma unroll
        for (int q = 0; q < 4; ++q) {
#pragma unroll
            for (int rr = 0; rr < 4; ++rr) {
                int reg = q * 4 + rr;
                int el = esub * 32 + q * 8 + half * 4 + rr;
                int e = e0 + el;
                if (e >= E) continue;
                float4 sv = *(const float4*)(sh + (size_t)e * 4);
                float a0 = acc0[reg] + red[(((esub * 4 + 0) * 16 + reg) << 6) + lane];
                float o0 = sv.y * accB[reg] + accC0[reg] + red[(((esub * 4 + 1) * 16 + reg) << 6) + lane];
                float o1 = sv.z * accB[reg] + accC1[reg] + red[(((esub * 4 + 2) * 16 + reg) << 6) + lane];
                float o2 = sv.w * accB[reg] + accC2[reg] + red[(((esub * 4 + 3) * 16 + reg) << 6) + lane];
                float* tpe = tp + (size_t)posbuf[el] * 128;   // CSR-ordered row
                tpe[col] = a0;
                tpe[32 + col * 3 + 0] = o0;
                tpe[32 + col * 3 + 1] = o1;
                tpe[32 + col * 3 + 2] = o2;
            }
        }
    }
}

// ---- K4: per-node gather-mean over CONTIGUOUS CSR-ordered tp rows ----
// R9-verified config (1024 blocks).
__global__ __launch_bounds__(256) void k4_gather(const float* __restrict__ tp,
                                                 const int* __restrict__ rowptr,
                                                 const float* __restrict__ na,
                                                 float* __restrict__ pre,
                                                 float* __restrict__ stats, int N) {
    __shared__ float bns[96];
    const int tid = threadIdx.x;
    if (tid < 96) bns[tid] = 0.f;
    __syncthreads();
    const int o = tid & 127, hf = tid >> 7;
    for (int n = blockIdx.x * 2 + hf; n < N; n += gridDim.x * 2) {
        int r0 = rowptr[n], r1 = rowptr[n + 1];
        float s = 0.f;
        int j = r0;
        for (; j + 4 <= r1; j += 4) {
            float t0 = tp[(size_t)(j + 0) * 128 + o];
            float t1 = tp[(size_t)(j + 1) * 128 + o];
            float t2 = tp[(size_t)(j + 2) * 128 + o];
            float t3 = tp[(size_t)(j + 3) * 128 + o];
            s += (t0 + t1) + (t2 + t3);
        }
        for (; j < r1; ++j)
            s += tp[(size_t)j * 128 + o];
        int dg = r1 - r0;
        float cf = (float)(dg > 0 ? dg : 1);
        float v = s / cf + na[(size_t)n * 128 + o];
        pre[(size_t)n * 128 + o] = v;
        if (o < 32) {
            atomicAdd(&bns[o], v);
            atomicAdd(&bns[32 + o], v * v);
        } else {
            atomicAdd(&bns[64 + (o - 32) / 3], v * v);
        }
    }
    __syncthreads();
    if (tid < 96) atomicAdd(&stats[tid], bns[tid]);
}

// ---- K5: apply batch norm ----
__global__ __launch_bounds__(256) void k5_bn(const float* __restrict__ pre,
                                             const float* __restrict__ stats,
                                             const float* __restrict__ bnw,
                                             const float* __restrict__ bnb,
                                             float* __restrict__ out, int N) {
    size_t idx = (size_t)blockIdx.x * 256 + threadIdx.x;
    if (idx >= (size_t)N * 128) return;
    int o = (int)(idx & 127);
    float v = pre[idx];
    float invN = 1.f / (float)N;
    if (o < 32) {
        float m   = stats[o] * invN;
        float var = stats[32 + o] * invN - m * m;
        out[idx] = (v - m) * rsqrtf(var + EPSV) * bnw[o] + bnb[o];
    } else {
        int j = (o - 32) / 3;
        float vn = rsqrtf(stats[64 + j] * invN * (1.f / 3.f) + EPSV);
        out[idx] = v * vn * bnw[32 + j];
    }
}

extern "C" void kernel_launch(void* const* d_in, const int* in_sizes, int n_in,
                              void* d_out, int out_size, void* d_ws, size_t ws_size,
                              hipStream_t stream) {
    const float* node_attr  = (const float*)d_in[0];
    const int*   edge_index = (const int*)d_in[1];
    const float* edge_attr  = (const float*)d_in[2];
    const float* edge_sh    = (const float*)d_in[3];
    const float* W1  = (const float*)d_in[4];
    const float* b1  = (const float*)d_in[5];
    const float* W2  = (const float*)d_in[6];
    const float* b2  = (const float*)d_in[7];
    const float* bnw = (const float*)d_in[8];
    const float* bnb = (const float*)d_in[9];

    const int N = in_sizes[0] / 128;
    const int E = in_sizes[1] / 2;
    const int ngroups = ((E + 127) / 128) * 4;

    float* tp     = (float*)d_ws;                 // E*128 (CSR-ordered rows)
    float* pre    = tp + (size_t)E * 128;         // N*128
    float* stats  = pre + (size_t)N * 128;        // 96
    int*   deg    = (int*)(stats + 96);           // N
    int*   cursor = deg + N;                      // N
    int*   rowptr = cursor + N;                   // N+1
    char* pbase = (char*)(rowptr + N + 1);
    pbase += (16 - ((size_t)pbase & 15)) & 15;    // align 16
    unsigned short* hsw = (unsigned short*)pbase;          // ngroups*4096 bf16
    unsigned short* W2T = hsw + (size_t)ngroups * 4096;    // 524288
    unsigned short* W1T = W2T + (size_t)524288;            // 16384

    // zero stats+deg+cursor (contiguous) in one capture-safe memset
    hipMemsetAsync(stats, 0, (96 + 2 * (size_t)N) * sizeof(int), stream);

    k0_tile<<<132 + (E + 255) / 256, 256, 0, stream>>>(W2, W1, W2T, W1T,
                                                       edge_index, deg, E);
    k1_fc<<<(E + 31) / 32 + 1, 64, 0, stream>>>(edge_attr, W1T, b1, hsw,
                                                deg, rowptr, N, E);
    k2_mfma<<<(E + 63) / 64, 256, 0, stream>>>(hsw, W2T, b2, node_attr, edge_index,
                                               edge_sh, rowptr, cursor, tp, E);
    k4_gather<<<1024, 256, 0, stream>>>(tp, rowptr, node_attr, pre, stats, N);
    size_t ntot = (size_t)N * 128;
    k5_bn<<<(int)((ntot + 255) / 256), 256, 0, stream>>>(pre, stats, bnw, bnb,
                                                         (float*)d_out, N);
}

// Round 13
// 282.998 us; speedup vs baseline: 1.0483x; 1.0483x over previous
//
#include <hip/hip_runtime.h>
#include <math.h>

#define EPSV 1e-5f
#define IS3  0.57735026918962576f   // 1/sqrt(3)
#define PNRM 0.125f                 // 1/sqrt(2*32)

typedef __attribute__((ext_vector_type(8)))  short  short8;
typedef __attribute__((ext_vector_type(16))) float  floatx16;

static __device__ inline unsigned short f2bf(float f) {
    unsigned int u = __float_as_uint(f);
    return (unsigned short)((u + 0x7fff + ((u >> 16) & 1)) >> 16);  // RNE
}
static __device__ inline float bflo(unsigned int u) { return __uint_as_float(u << 16); }
static __device__ inline float bfhi(unsigned int u) { return __uint_as_float(u & 0xffff0000u); }

// async global->LDS, 16B per lane; lds dest = uniform base + lane*16 (HW adds it)
#define GLD16(gp, lp) __builtin_amdgcn_global_load_lds( \
    (const __attribute__((address_space(1))) unsigned int*)(gp), \
    (__attribute__((address_space(3))) unsigned int*)(lp), 16, 0, 0)

// ---- K0: weight tiling + deg count + ea->bf16 pre-conversion.
// blocks 0..127: W2 col-tiles; 128..131: W1 col-tiles;
// 132..132+DEGB-1: deg atomics; rest: coalesced ea f32->bf16 (8 elems/thr).
// Pre-converting ea halves k1's scattered A-load count and deletes all
// A-path f2bf in k1 (numerically identical: same RNE convert before MFMA).
__global__ __launch_bounds__(256) void k0_tile(const float* __restrict__ W2,
                                               const float* __restrict__ W1,
                                               unsigned short* __restrict__ W2T,
                                               unsigned short* __restrict__ W1T,
                                               const int* __restrict__ ei,
                                               int* __restrict__ deg,
                                               const float* __restrict__ ea,
                                               unsigned short* __restrict__ eabf,
                                               int degb, int E) {
    const int bx = blockIdx.x, tid = threadIdx.x;
    if (bx >= 132 + degb) {
        // ea -> bf16, 8 elems per thread, fully coalesced
        size_t i8 = ((size_t)(bx - 132 - degb) * 256 + tid) * 8;
        size_t total = (size_t)E * 128;
        if (i8 < total) {
            const float4* p = (const float4*)(ea + i8);
            float4 f0 = p[0], f1 = p[1];
            short8 v;
            v[0] = (short)f2bf(f0.x); v[1] = (short)f2bf(f0.y);
            v[2] = (short)f2bf(f0.z); v[3] = (short)f2bf(f0.w);
            v[4] = (short)f2bf(f1.x); v[5] = (short)f2bf(f1.y);
            v[6] = (short)f2bf(f1.z); v[7] = (short)f2bf(f1.w);
            *(short8*)(eabf + i8) = v;
        }
        return;
    }
    if (bx >= 132) {
        int e = (bx - 132) * 256 + tid;
        if (e < E) atomicAdd(&deg[ei[e]], 1);
        return;
    }
    __shared__ float tile[128 * 33];
    const float* src;
    unsigned short* dst;
    int nc, tb;
    if (bx < 128) { src = W2; dst = W2T; nc = 4096; tb = bx; }
    else          { src = W1; dst = W1T; nc = 128;  tb = bx - 128; }
    const int c0 = tb * 32;
#pragma unroll
    for (int r = 0; r < 16; ++r) {
        int lin = r * 256 + tid;
        int k = lin >> 5, c = lin & 31;
        tile[k * 33 + c] = src[(size_t)k * nc + c0 + c];
    }
    __syncthreads();
#pragma unroll
    for (int r = 0; r < 2; ++r) {
        int g = r * 256 + tid;          // 0..511
        int kc = g >> 5, c = g & 31;
        short8 v;
#pragma unroll
        for (int j = 0; j < 8; ++j)
            v[j] = (short)f2bf(tile[(kc * 8 + j) * 33 + c]);
        *(short8*)(dst + (size_t)tb * 4096 + kc * 256 + c * 8) = v;
    }
}

// ---- K1: h = relu(ea @ W1 + b1) via MFMA 32x32x16 — R9 STRUCTURE EXACT
// (128 edges/block, 4 waves, staged W1T, one barrier, scan in last block).
// Only change: A-fragments load from PRE-CONVERTED bf16 eabf -- one 16B
// load per c (was 2x float4 + 16 f2bf). Per-lane scattered loads 16 -> 8.
// h layout: group g = e/32: g*4096 + (k>>3)*256 + (e&31)*8 + (k&7).
__global__ __launch_bounds__(256) void k1_fc(const unsigned short* __restrict__ eabf,
                                             const unsigned short* __restrict__ W1T,
                                             const float* __restrict__ b1,
                                             unsigned short* __restrict__ hsw,
                                             const int* __restrict__ deg,
                                             int* __restrict__ rowptr,
                                             int N, int E) {
    __shared__ __align__(16) unsigned short W1s[16384];     // 32 KB swizzled tiles
    __shared__ __align__(16) unsigned short bounce[4 * 1056];  // 8.4 KB
    const int tid = threadIdx.x, lane = tid & 63, wv = tid >> 6;
    const int half = lane >> 5, col = lane & 31;
    const int nfc = (E + 127) / 128;

    if (blockIdx.x >= nfc) {
        // exclusive prefix sum deg -> rowptr (256 threads; LDS aliases W1s)
        int* part = (int*)W1s;
        const int chunk = (N + 255) / 256;
        const int base = tid * chunk;
        int s = 0;
        for (int i = 0; i < chunk; ++i) {
            int n = base + i;
            if (n < N) s += deg[n];
        }
        part[tid] = s;
        __syncthreads();
        for (int off = 1; off < 256; off <<= 1) {
            int t = 0;
            if (tid >= off) t = part[tid - off];
            __syncthreads();
            if (tid >= off) part[tid] += t;
            __syncthreads();
        }
        int prefix = (tid == 0) ? 0 : part[tid - 1];
        for (int i = 0; i < chunk; ++i) {
            int n = base + i;
            if (n < N) { rowptr[n] = prefix; prefix += deg[n]; }
        }
        if (tid == 0) rowptr[N] = part[255];
        return;
    }

    const int e0 = blockIdx.x * 128;

#pragma unroll
    for (int q = 0; q < 8; ++q) {
        int chunk = wv * 8 + q;
        GLD16((const char*)W1T + chunk * 1024 + lane * 16, (char*)W1s + chunk * 1024);
    }

    int e = e0 + wv * 32 + col; if (e >= E) e = E - 1;
    short8 afr[8];
#pragma unroll
    for (int c = 0; c < 8; ++c)
        afr[c] = *(const short8*)(eabf + (size_t)e * 128 + c * 16 + half * 8);
    __syncthreads();

    unsigned short* myb = bounce + wv * 1056;   // 4 chunks x 264 shorts
    const int gg = blockIdx.x * 4 + wv;
#pragma unroll
    for (int jt = 0; jt < 4; ++jt) {
        floatx16 d = {0,0,0,0,0,0,0,0,0,0,0,0,0,0,0,0};
#pragma unroll
        for (int c = 0; c < 8; ++c) {
            short8 bf = *(const short8*)((const char*)W1s + jt * 8192 + (2 * c + half) * 512 + col * 16);
            d = __builtin_amdgcn_mfma_f32_32x32x16_bf16(afr[c], bf, d, 0, 0, 0);
        }
        float b1v = b1[jt * 32 + col];
#pragma unroll
        for (int reg = 0; reg < 16; ++reg) {
            int r = (reg & 3) + 8 * (reg >> 2) + 4 * half;
            float v = d[reg] + b1v;
            v = v > 0.f ? v : 0.f;
            myb[(col >> 3) * 264 + r * 8 + (col & 7)] = f2bf(v);
        }
#pragma unroll
        for (int s = 0; s < 2; ++s) {
            short8 v = *(const short8*)&myb[(s * 2 + (lane >> 5)) * 264 + (lane & 31) * 8];
            *(short8*)(hsw + (size_t)gg * 4096 + jt * 1024 + s * 512 + lane * 8) = v;
        }
    }
}

// ---- K2: MFMA 32x32x16 GEMM (h @ W2) fused with TP contraction.
// EXACT R9 kernel (verified 112us): barrier-free hot loop, posbuf CSR slots,
// CSR-ordered tp row stores. DO NOT TOUCH.
__global__ __launch_bounds__(256, 2) void k2_mfma(const unsigned short* __restrict__ hsw,
                                                  const unsigned short* __restrict__ W2T,
                                                  const float* __restrict__ b2,
                                                  const float* __restrict__ na,
                                                  const int* __restrict__ ei,
                                                  const float* __restrict__ sh,
                                                  const int* __restrict__ rowptr,
                                                  int* __restrict__ cursor,
                                                  float* __restrict__ tp, int E) {
    __shared__ __align__(16) char smem[32768];
    __shared__ int posbuf[64];                     // edge -> CSR slot (this block)
    unsigned short* Ctb = (unsigned short*)smem;   // 6 x 4 KB coef tables
    float* red = (float*)smem;                     // 32 KB epilogue alias

    const int tid = threadIdx.x, lane = tid & 63, wv = tid >> 6;
    const int half = lane >> 5, col = lane & 31;
    const int ust = wv >> 1, esub = wv & 1;
    const int e0 = blockIdx.x * 64;

    // merged k_fill: claim CSR slots for this block's edges (no elist store)
    if (tid < 64) {
        int e = e0 + tid;
        if (e < E) {
            int s = ei[e];
            posbuf[tid] = rowptr[s] + atomicAdd(&cursor[s], 1);
        }
    }

    // coef tables (bf16), [u][el], pre-scaled by PNRM / PNRM*IS3 / s0
    for (int idx = tid; idx < 2048; idx += 256) {
        int el = idx & 63, u = idx >> 6;
        int e = e0 + el; int ec = e < E ? e : E - 1;
        int dn = ei[E + ec];
        const float* nar = na + (size_t)dn * 128;
        float x0  = nar[u];
        float x10 = nar[32 + u * 3], x11 = nar[33 + u * 3], x12 = nar[34 + u * 3];
        const float* shr = sh + (size_t)ec * 4;
        float s0 = shr[0], s1 = shr[1], s2 = shr[2], s3 = shr[3];
        int o = u * 64 + el;
        Ctb[0 * 2048 + o] = f2bf(PNRM * x0 * s0);
        Ctb[1 * 2048 + o] = f2bf(PNRM * IS3 * x0);
        Ctb[2 * 2048 + o] = f2bf(PNRM * IS3 * s0 * x10);
        Ctb[3 * 2048 + o] = f2bf(PNRM * IS3 * s0 * x11);
        Ctb[4 * 2048 + o] = f2bf(PNRM * IS3 * s0 * x12);
        Ctb[5 * 2048 + o] = f2bf(PNRM * IS3 * (x10 * s1 + x11 * s2 + x12 * s3));
    }

    // A fragments direct from swizzled h (coalesced 512B/half-wave)
    const int gg = blockIdx.x * 2 + esub;
    short8 afr[8];
#pragma unroll
    for (int c = 0; c < 8; ++c)
        afr[c] = *(const short8*)(hsw + (size_t)gg * 4096 + (2 * c + half) * 256 + col * 8);

    __syncthreads();

    float acc0[16] = {}, accB[16] = {}, accC0[16] = {}, accC1[16] = {}, accC2[16] = {};
    const int elb0 = esub * 32 + half * 4;
    const unsigned short* bbase = W2T + half * 256 + col * 8;

#define LOADB(p, br, b2r) do {                                         \
        int _ct = 2 * (p) + ust;                                       \
        const unsigned short* _bp = bbase + (size_t)_ct * 4096;        \
        _Pragma("unroll")                                              \
        for (int _c = 0; _c < 8; ++_c)                                 \
            (br)[_c] = *(const short8*)(_bp + _c * 512);               \
        (b2r) = b2[_ct * 32 + col];                                    \
    } while (0)

#define COMPUTE(p, br, b2v) do {                                                              \
        const int _ct = 2 * (p) + ust;                                                        \
        const int _b = _ct >> 5, _u = _ct & 31;                                               \
        floatx16 d = {0,0,0,0,0,0,0,0,0,0,0,0,0,0,0,0};                                       \
        _Pragma("unroll")                                                                     \
        for (int _c = 0; _c < 8; ++_c)                                                        \
            d = __builtin_amdgcn_mfma_f32_32x32x16_bf16(afr[_c], (br)[_c], d, 0, 0, 0);       \
        if (_b == 0 || _b == 3) {                                                             \
            const unsigned short* tb = Ctb + (_b == 0 ? 0 : 5) * 2048;                        \
            _Pragma("unroll")                                                                 \
            for (int q = 0; q < 4; ++q) {                                                     \
                uint2 cv = *(const uint2*)&tb[_u * 64 + elb0 + q * 8];                        \
                acc0[q * 4 + 0] += bflo(cv.x) * (d[q * 4 + 0] + (b2v));                       \
                acc0[q * 4 + 1] += bfhi(cv.x) * (d[q * 4 + 1] + (b2v));                       \
                acc0[q * 4 + 2] += bflo(cv.y) * (d[q * 4 + 2] + (b2v));                       \
                acc0[q * 4 + 3] += bfhi(cv.y) * (d[q * 4 + 3] + (b2v));                       \
            }                                                                                 \
        } else if (_b == 1) {                                                                 \
            _Pragma("unroll")                                                                 \
            for (int q = 0; q < 4; ++q) {                                                     \
                uint2 cv = *(const uint2*)&Ctb[1 * 2048 + _u * 64 + elb0 + q * 8];            \
                accB[q * 4 + 0] += bflo(cv.x) * (d[q * 4 + 0] + (b2v));                       \
                accB[q * 4 + 1] += bfhi(cv.x) * (d[q * 4 + 1] + (b2v));                       \
                accB[q * 4 + 2] += bflo(cv.y) * (d[q * 4 + 2] + (b2v));                       \
                accB[q * 4 + 3] += bfhi(cv.y) * (d[q * 4 + 3] + (b2v));                       \
            }                                                                                 \
        } else {                                                                              \
            _Pragma("unroll")                                                                 \
            for (int q = 0; q < 4; ++q) {                                                     \
                uint2 cu0 = *(const uint2*)&Ctb[2 * 2048 + _u * 64 + elb0 + q * 8];           \
                uint2 cu1 = *(const uint2*)&Ctb[3 * 2048 + _u * 64 + elb0 + q * 8];           \
                uint2 cu2 = *(const uint2*)&Ctb[4 * 2048 + _u * 64 + elb0 + q * 8];           \
                float f0[4] = {bflo(cu0.x), bfhi(cu0.x), bflo(cu0.y), bfhi(cu0.y)};           \
                float f1[4] = {bflo(cu1.x), bfhi(cu1.x), bflo(cu1.y), bfhi(cu1.y)};           \
                float f2[4] = {bflo(cu2.x), bfhi(cu2.x), bflo(cu2.y), bfhi(cu2.y)};           \
                _Pragma("unroll")                                                             \
                for (int rr = 0; rr < 4; ++rr) {                                              \
                    float v = d[q * 4 + rr] + (b2v);                                          \
                    accC0[q * 4 + rr] += f0[rr] * v;                                          \
                    accC1[q * 4 + rr] += f1[rr] * v;                                          \
                    accC2[q * 4 + rr] += f2[rr] * v;                                          \
                }                                                                             \
            }                                                                                 \
        }                                                                                     \
    } while (0)

    short8 bA[8], bB[8], bC[8];
    float b2A, b2B, b2C;
    LOADB(0, bA, b2A); LOADB(1, bB, b2B); LOADB(2, bC, b2C);
    for (int p = 0; p < 60; p += 3) {
        COMPUTE(p,     bA, b2A); LOADB(p + 3, bA, b2A);
        COMPUTE(p + 1, bB, b2B); LOADB(p + 4, bB, b2B);
        COMPUTE(p + 2, bC, b2C); LOADB(p + 5, bC, b2C);
    }
    COMPUTE(60, bA, b2A); LOADB(63, bA, b2A);
    COMPUTE(61, bB, b2B);
    COMPUTE(62, bC, b2C);
    COMPUTE(63, bA, b2A);
#undef LOADB
#undef COMPUTE

    // epilogue: combine the two u-streams via LDS (red aliases Ctb)
    __syncthreads();
    if (ust == 1) {
#pragma unroll
        for (int q = 0; q < 4; ++q) {
#pragma unroll
            for (int rr = 0; rr < 4; ++rr) {
                int reg = q * 4 + rr;
                int el = esub * 32 + q * 8 + half * 4 + rr;
                int e = e0 + el; int ec = e < E ? e : E - 1;
                float4 sv = *(const float4*)(sh + (size_t)ec * 4);
                red[(((esub * 4 + 0) * 16 + reg) << 6) + lane] = acc0[reg];
                red[(((esub * 4 + 1) * 16 + reg) << 6) + lane] = sv.y * accB[reg] + accC0[reg];
                red[(((esub * 4 + 2) * 16 + reg) << 6) + lane] = sv.z * accB[reg] + accC1[reg];
                red[(((esub * 4 + 3) * 16 + reg) << 6) + lane] = sv.w * accB[reg] + accC2[reg];
            }
        }
    }
    __syncthreads();
    if (ust == 0) {
#pragma unroll
        for (int q = 0; q < 4; ++q) {
#pragma unroll
            for (int rr = 0; rr < 4; ++rr) {
                int reg = q * 4 + rr;
                int el = esub * 32 + q * 8 + half * 4 + rr;
                int e = e0 + el;
                if (e >= E) continue;
                float4 sv = *(const float4*)(sh + (size_t)e * 4);
                float a0 = acc0[reg] + red[(((esub * 4 + 0) * 16 + reg) << 6) + lane];
                float o0 = sv.y * accB[reg] + accC0[reg] + red[(((esub * 4 + 1) * 16 + reg) << 6) + lane];
                float o1 = sv.z * accB[reg] + accC1[reg] + red[(((esub * 4 + 2) * 16 + reg) << 6) + lane];
                float o2 = sv.w * accB[reg] + accC2[reg] + red[(((esub * 4 + 3) * 16 + reg) << 6) + lane];
                float* tpe = tp + (size_t)posbuf[el] * 128;   // CSR-ordered row
                tpe[col] = a0;
                tpe[32 + col * 3 + 0] = o0;
                tpe[32 + col * 3 + 1] = o1;
                tpe[32 + col * 3 + 2] = o2;
            }
        }
    }
}

// ---- K4: per-node gather-mean over CONTIGUOUS CSR-ordered tp rows ----
// Latency-bound (R10: time ~ 1/blocks) -> 2048 blocks.
__global__ __launch_bounds__(256) void k4_gather(const float* __restrict__ tp,
                                                 const int* __restrict__ rowptr,
                                                 const float* __restrict__ na,
                                                 float* __restrict__ pre,
                                                 float* __restrict__ stats, int N) {
    __shared__ float bns[96];
    const int tid = threadIdx.x;
    if (tid < 96) bns[tid] = 0.f;
    __syncthreads();
    const int o = tid & 127, hf = tid >> 7;
    for (int n = blockIdx.x * 2 + hf; n < N; n += gridDim.x * 2) {
        int r0 = rowptr[n], r1 = rowptr[n + 1];
        float s = 0.f;
        int j = r0;
        for (; j + 4 <= r1; j += 4) {
            float t0 = tp[(size_t)(j + 0) * 128 + o];
            float t1 = tp[(size_t)(j + 1) * 128 + o];
            float t2 = tp[(size_t)(j + 2) * 128 + o];
            float t3 = tp[(size_t)(j + 3) * 128 + o];
            s += (t0 + t1) + (t2 + t3);
        }
        for (; j < r1; ++j)
            s += tp[(size_t)j * 128 + o];
        int dg = r1 - r0;
        float cf = (float)(dg > 0 ? dg : 1);
        float v = s / cf + na[(size_t)n * 128 + o];
        pre[(size_t)n * 128 + o] = v;
        if (o < 32) {
            atomicAdd(&bns[o], v);
            atomicAdd(&bns[32 + o], v * v);
        } else {
            atomicAdd(&bns[64 + (o - 32) / 3], v * v);
        }
    }
    __syncthreads();
    if (tid < 96) atomicAdd(&stats[tid], bns[tid]);
}

// ---- K5: apply batch norm ----
__global__ __launch_bounds__(256) void k5_bn(const float* __restrict__ pre,
                                             const float* __restrict__ stats,
                                             const float* __restrict__ bnw,
                                             const float* __restrict__ bnb,
                                             float* __restrict__ out, int N) {
    size_t idx = (size_t)blockIdx.x * 256 + threadIdx.x;
    if (idx >= (size_t)N * 128) return;
    int o = (int)(idx & 127);
    float v = pre[idx];
    float invN = 1.f / (float)N;
    if (o < 32) {
        float m   = stats[o] * invN;
        float var = stats[32 + o] * invN - m * m;
        out[idx] = (v - m) * rsqrtf(var + EPSV) * bnw[o] + bnb[o];
    } else {
        int j = (o - 32) / 3;
        float vn = rsqrtf(stats[64 + j] * invN * (1.f / 3.f) + EPSV);
        out[idx] = v * vn * bnw[32 + j];
    }
}

extern "C" void kernel_launch(void* const* d_in, const int* in_sizes, int n_in,
                              void* d_out, int out_size, void* d_ws, size_t ws_size,
                              hipStream_t stream) {
    const float* node_attr  = (const float*)d_in[0];
    const int*   edge_index = (const int*)d_in[1];
    const float* edge_attr  = (const float*)d_in[2];
    const float* edge_sh    = (const float*)d_in[3];
    const float* W1  = (const float*)d_in[4];
    const float* b1  = (const float*)d_in[5];
    const float* W2  = (const float*)d_in[6];
    const float* b2  = (const float*)d_in[7];
    const float* bnw = (const float*)d_in[8];
    const float* bnb = (const float*)d_in[9];

    const int N = in_sizes[0] / 128;
    const int E = in_sizes[1] / 2;
    const int ngroups = ((E + 127) / 128) * 4;

    float* tp     = (float*)d_ws;                 // E*128 (CSR-ordered rows)
    float* pre    = tp + (size_t)E * 128;         // N*128
    float* stats  = pre + (size_t)N * 128;        // 96
    int*   deg    = (int*)(stats + 96);           // N
    int*   cursor = deg + N;                      // N
    int*   rowptr = cursor + N;                   // N+1
    char* pbase = (char*)(rowptr + N + 1);
    pbase += (16 - ((size_t)pbase & 15)) & 15;    // align 16
    unsigned short* hsw = (unsigned short*)pbase;          // ngroups*4096 bf16
    unsigned short* W2T = hsw + (size_t)ngroups * 4096;    // 524288
    unsigned short* W1T = W2T + (size_t)524288;            // 16384

    // eabf (E*128 bf16 = 15.4 MB) ALIASES tp (30.7 MB): written by k0,
    // consumed by k1; k2 overwrites tp only after k1 completes (stream order).
    unsigned short* eabf = (unsigned short*)tp;

    // zero stats+deg+cursor (contiguous) in one capture-safe memset
    hipMemsetAsync(stats, 0, (96 + 2 * (size_t)N) * sizeof(int), stream);

    const int degb  = (E + 255) / 256;
    const int convb = (int)(((size_t)E * 128 / 8 + 255) / 256);
    k0_tile<<<132 + degb + convb, 256, 0, stream>>>(W2, W1, W2T, W1T,
                                                    edge_index, deg,
                                                    edge_attr, eabf, degb, E);
    k1_fc<<<(E + 127) / 128 + 1, 256, 0, stream>>>(eabf, W1T, b1, hsw,
                                                   deg, rowptr, N, E);
    k2_mfma<<<(E + 63) / 64, 256, 0, stream>>>(hsw, W2T, b2, node_attr, edge_index,
                                               edge_sh, rowptr, cursor, tp, E);
    k4_gather<<<2048, 256, 0, stream>>>(tp, rowptr, node_attr, pre, stats, N);
    size_t ntot = (size_t)N * 128;
    k5_bn<<<(int)((ntot + 255) / 256), 256, 0, stream>>>(pre, stats, bnw, bnb,
                                                         (float*)d_out, N);
}

// Round 14
// 254.321 us; speedup vs baseline: 1.1665x; 1.1128x over previous
//
#include <hip/hip_runtime.h>
#include <math.h>

#define EPSV 1e-5f
#define IS3  0.57735026918962576f   // 1/sqrt(3)
#define PNRM 0.125f                 // 1/sqrt(2*32)

typedef __attribute__((ext_vector_type(8)))  short  short8;
typedef __attribute__((ext_vector_type(16))) float  floatx16;

static __device__ inline unsigned short f2bf(float f) {
    unsigned int u = __float_as_uint(f);
    return (unsigned short)((u + 0x7fff + ((u >> 16) & 1)) >> 16);  // RNE
}
static __device__ inline float bflo(unsigned int u) { return __uint_as_float(u << 16); }
static __device__ inline float bfhi(unsigned int u) { return __uint_as_float(u & 0xffff0000u); }

// async global->LDS, 16B per lane; lds dest = uniform base + lane*16 (HW adds it)
#define GLD16(gp, lp) __builtin_amdgcn_global_load_lds( \
    (const __attribute__((address_space(1))) unsigned int*)(gp), \
    (__attribute__((address_space(3))) unsigned int*)(lp), 16, 0, 0)

// ---- K0: coalesced LDS-transpose f32 -> bf16 swizzled col-tiles, + deg count.
// blocks 0..127: W2 col-tiles; 128..131: W1 col-tiles; 132+: deg atomics
// tile layout (shorts): tile*4096 + kc*256 + (c&31)*8 + k7
__global__ __launch_bounds__(256) void k0_tile(const float* __restrict__ W2,
                                               const float* __restrict__ W1,
                                               unsigned short* __restrict__ W2T,
                                               unsigned short* __restrict__ W1T,
                                               const int* __restrict__ ei,
                                               int* __restrict__ deg, int E) {
    const int bx = blockIdx.x, tid = threadIdx.x;
    if (bx >= 132) {
        int e = (bx - 132) * 256 + tid;
        if (e < E) atomicAdd(&deg[ei[e]], 1);
        return;
    }
    __shared__ float tile[128 * 33];
    const float* src;
    unsigned short* dst;
    int nc, tb;
    if (bx < 128) { src = W2; dst = W2T; nc = 4096; tb = bx; }
    else          { src = W1; dst = W1T; nc = 128;  tb = bx - 128; }
    const int c0 = tb * 32;
#pragma unroll
    for (int r = 0; r < 16; ++r) {
        int lin = r * 256 + tid;
        int k = lin >> 5, c = lin & 31;
        tile[k * 33 + c] = src[(size_t)k * nc + c0 + c];
    }
    __syncthreads();
#pragma unroll
    for (int r = 0; r < 2; ++r) {
        int g = r * 256 + tid;          // 0..511
        int kc = g >> 5, c = g & 31;
        short8 v;
#pragma unroll
        for (int j = 0; j < 8; ++j)
            v[j] = (short)f2bf(tile[(kc * 8 + j) * 33 + c]);
        *(short8*)(dst + (size_t)tb * 4096 + kc * 256 + c * 8) = v;
    }
}

// ---- K1: h = relu(ea @ W1 + b1) via MFMA 32x32x16, PURE GEMM blocks,
// plus ONE extra block (last) doing the deg->rowptr exclusive scan.
// h layout: group g = e/32: short addr = g*4096 + (k>>3)*256 + (e&31)*8 + (k&7).
__global__ __launch_bounds__(256) void k1_fc(const float* __restrict__ ea,
                                             const unsigned short* __restrict__ W1T,
                                             const float* __restrict__ b1,
                                             unsigned short* __restrict__ hsw,
                                             const int* __restrict__ deg,
                                             int* __restrict__ rowptr,
                                             int N, int E) {
    __shared__ __align__(16) unsigned short W1s[16384];     // 32 KB swizzled tiles
    __shared__ __align__(16) unsigned short bounce[4 * 1056];  // 8.4 KB
    const int tid = threadIdx.x, lane = tid & 63, wv = tid >> 6;
    const int half = lane >> 5, col = lane & 31;
    const int nfc = (E + 127) / 128;

    if (blockIdx.x >= nfc) {
        // exclusive prefix sum deg -> rowptr (256 threads; LDS aliases W1s)
        int* part = (int*)W1s;
        const int chunk = (N + 255) / 256;
        const int base = tid * chunk;
        int s = 0;
        for (int i = 0; i < chunk; ++i) {
            int n = base + i;
            if (n < N) s += deg[n];
        }
        part[tid] = s;
        __syncthreads();
        for (int off = 1; off < 256; off <<= 1) {
            int t = 0;
            if (tid >= off) t = part[tid - off];
            __syncthreads();
            if (tid >= off) part[tid] += t;
            __syncthreads();
        }
        int prefix = (tid == 0) ? 0 : part[tid - 1];
        for (int i = 0; i < chunk; ++i) {
            int n = base + i;
            if (n < N) { rowptr[n] = prefix; prefix += deg[n]; }
        }
        if (tid == 0) rowptr[N] = part[255];
        return;
    }

    const int e0 = blockIdx.x * 128;

#pragma unroll
    for (int q = 0; q < 8; ++q) {
        int chunk = wv * 8 + q;
        GLD16((const char*)W1T + chunk * 1024 + lane * 16, (char*)W1s + chunk * 1024);
    }

    int e = e0 + wv * 32 + col; if (e >= E) e = E - 1;
    short8 afr[8];
#pragma unroll
    for (int c = 0; c < 8; ++c) {
        const float4* p = (const float4*)(ea + (size_t)e * 128 + c * 16 + half * 8);
        float4 f0 = p[0], f1 = p[1];
        short8 v;
        v[0] = (short)f2bf(f0.x); v[1] = (short)f2bf(f0.y);
        v[2] = (short)f2bf(f0.z); v[3] = (short)f2bf(f0.w);
        v[4] = (short)f2bf(f1.x); v[5] = (short)f2bf(f1.y);
        v[6] = (short)f2bf(f1.z); v[7] = (short)f2bf(f1.w);
        afr[c] = v;
    }
    __syncthreads();

    unsigned short* myb = bounce + wv * 1056;   // 4 chunks x 264 shorts
    const int gg = blockIdx.x * 4 + wv;
#pragma unroll
    for (int jt = 0; jt < 4; ++jt) {
        floatx16 d = {0,0,0,0,0,0,0,0,0,0,0,0,0,0,0,0};
#pragma unroll
        for (int c = 0; c < 8; ++c) {
            short8 bf = *(const short8*)((const char*)W1s + jt * 8192 + (2 * c + half) * 512 + col * 16);
            d = __builtin_amdgcn_mfma_f32_32x32x16_bf16(afr[c], bf, d, 0, 0, 0);
        }
        float b1v = b1[jt * 32 + col];
#pragma unroll
        for (int reg = 0; reg < 16; ++reg) {
            int r = (reg & 3) + 8 * (reg >> 2) + 4 * half;
            float v = d[reg] + b1v;
            v = v > 0.f ? v : 0.f;
            myb[(col >> 3) * 264 + r * 8 + (col & 7)] = f2bf(v);
        }
#pragma unroll
        for (int s = 0; s < 2; ++s) {
            short8 v = *(const short8*)&myb[(s * 2 + (lane >> 5)) * 264 + (lane & 31) * 8];
            *(short8*)(hsw + (size_t)gg * 4096 + jt * 1024 + s * 512 + lane * 8) = v;
        }
    }
}

// ---- K2: MFMA 32x32x16 GEMM (h @ W2) fused with TP contraction.
// EXACT R9 kernel (verified 112us): barrier-free hot loop, posbuf CSR slots,
// CSR-ordered tp row stores. DO NOT TOUCH.
__global__ __launch_bounds__(256, 2) void k2_mfma(const unsigned short* __restrict__ hsw,
                                                  const unsigned short* __restrict__ W2T,
                                                  const float* __restrict__ b2,
                                                  const float* __restrict__ na,
                                                  const int* __restrict__ ei,
                                                  const float* __restrict__ sh,
                                                  const int* __restrict__ rowptr,
                                                  int* __restrict__ cursor,
                                                  float* __restrict__ tp, int E) {
    __shared__ __align__(16) char smem[32768];
    __shared__ int posbuf[64];                     // edge -> CSR slot (this block)
    unsigned short* Ctb = (unsigned short*)smem;   // 6 x 4 KB coef tables
    float* red = (float*)smem;                     // 32 KB epilogue alias

    const int tid = threadIdx.x, lane = tid & 63, wv = tid >> 6;
    const int half = lane >> 5, col = lane & 31;
    const int ust = wv >> 1, esub = wv & 1;
    const int e0 = blockIdx.x * 64;

    // merged k_fill: claim CSR slots for this block's edges (no elist store)
    if (tid < 64) {
        int e = e0 + tid;
        if (e < E) {
            int s = ei[e];
            posbuf[tid] = rowptr[s] + atomicAdd(&cursor[s], 1);
        }
    }

    // coef tables (bf16), [u][el], pre-scaled by PNRM / PNRM*IS3 / s0
    for (int idx = tid; idx < 2048; idx += 256) {
        int el = idx & 63, u = idx >> 6;
        int e = e0 + el; int ec = e < E ? e : E - 1;
        int dn = ei[E + ec];
        const float* nar = na + (size_t)dn * 128;
        float x0  = nar[u];
        float x10 = nar[32 + u * 3], x11 = nar[33 + u * 3], x12 = nar[34 + u * 3];
        const float* shr = sh + (size_t)ec * 4;
        float s0 = shr[0], s1 = shr[1], s2 = shr[2], s3 = shr[3];
        int o = u * 64 + el;
        Ctb[0 * 2048 + o] = f2bf(PNRM * x0 * s0);
        Ctb[1 * 2048 + o] = f2bf(PNRM * IS3 * x0);
        Ctb[2 * 2048 + o] = f2bf(PNRM * IS3 * s0 * x10);
        Ctb[3 * 2048 + o] = f2bf(PNRM * IS3 * s0 * x11);
        Ctb[4 * 2048 + o] = f2bf(PNRM * IS3 * s0 * x12);
        Ctb[5 * 2048 + o] = f2bf(PNRM * IS3 * (x10 * s1 + x11 * s2 + x12 * s3));
    }

    // A fragments direct from swizzled h (coalesced 512B/half-wave)
    const int gg = blockIdx.x * 2 + esub;
    short8 afr[8];
#pragma unroll
    for (int c = 0; c < 8; ++c)
        afr[c] = *(const short8*)(hsw + (size_t)gg * 4096 + (2 * c + half) * 256 + col * 8);

    __syncthreads();

    float acc0[16] = {}, accB[16] = {}, accC0[16] = {}, accC1[16] = {}, accC2[16] = {};
    const int elb0 = esub * 32 + half * 4;
    const unsigned short* bbase = W2T + half * 256 + col * 8;

#define LOADB(p, br, b2r) do {                                         \
        int _ct = 2 * (p) + ust;                                       \
        const unsigned short* _bp = bbase + (size_t)_ct * 4096;        \
        _Pragma("unroll")                                              \
        for (int _c = 0; _c < 8; ++_c)                                 \
            (br)[_c] = *(const short8*)(_bp + _c * 512);               \
        (b2r) = b2[_ct * 32 + col];                                    \
    } while (0)

#define COMPUTE(p, br, b2v) do {                                                              \
        const int _ct = 2 * (p) + ust;                                                        \
        const int _b = _ct >> 5, _u = _ct & 31;                                               \
        floatx16 d = {0,0,0,0,0,0,0,0,0,0,0,0,0,0,0,0};                                       \
        _Pragma("unroll")                                                                     \
        for (int _c = 0; _c < 8; ++_c)                                                        \
            d = __builtin_amdgcn_mfma_f32_32x32x16_bf16(afr[_c], (br)[_c], d, 0, 0, 0);       \
        if (_b == 0 || _b == 3) {                                                             \
            const unsigned short* tb = Ctb + (_b == 0 ? 0 : 5) * 2048;                        \
            _Pragma("unroll")                                                                 \
            for (int q = 0; q < 4; ++q) {                                                     \
                uint2 cv = *(const uint2*)&tb[_u * 64 + elb0 + q * 8];                        \
                acc0[q * 4 + 0] += bflo(cv.x) * (d[q * 4 + 0] + (b2v));                       \
                acc0[q * 4 + 1] += bfhi(cv.x) * (d[q * 4 + 1] + (b2v));                       \
                acc0[q * 4 + 2] += bflo(cv.y) * (d[q * 4 + 2] + (b2v));                       \
                acc0[q * 4 + 3] += bfhi(cv.y) * (d[q * 4 + 3] + (b2v));                       \
            }                                                                                 \
        } else if (_b == 1) {                                                                 \
            _Pragma("unroll")                                                                 \
            for (int q = 0; q < 4; ++q) {                                                     \
                uint2 cv = *(const uint2*)&Ctb[1 * 2048 + _u * 64 + elb0 + q * 8];            \
                accB[q * 4 + 0] += bflo(cv.x) * (d[q * 4 + 0] + (b2v));                       \
                accB[q * 4 + 1] += bfhi(cv.x) * (d[q * 4 + 1] + (b2v));                       \
                accB[q * 4 + 2] += bflo(cv.y) * (d[q * 4 + 2] + (b2v));                       \
                accB[q * 4 + 3] += bfhi(cv.y) * (d[q * 4 + 3] + (b2v));                       \
            }                                                                                 \
        } else {                                                                              \
            _Pragma("unroll")                                                                 \
            for (int q = 0; q < 4; ++q) {                                                     \
                uint2 cu0 = *(const uint2*)&Ctb[2 * 2048 + _u * 64 + elb0 + q * 8];           \
                uint2 cu1 = *(const uint2*)&Ctb[3 * 2048 + _u * 64 + elb0 + q * 8];           \
                uint2 cu2 = *(const uint2*)&Ctb[4 * 2048 + _u * 64 + elb0 + q * 8];           \
                float f0[4] = {bflo(cu0.x), bfhi(cu0.x), bflo(cu0.y), bfhi(cu0.y)};           \
                float f1[4] = {bflo(cu1.x), bfhi(cu1.x), bflo(cu1.y), bfhi(cu1.y)};           \
                float f2[4] = {bflo(cu2.x), bfhi(cu2.x), bflo(cu2.y), bfhi(cu2.y)};           \
                _Pragma("unroll")                                                             \
                for (int rr = 0; rr < 4; ++rr) {                                              \
                    float v = d[q * 4 + rr] + (b2v);                                          \
                    accC0[q * 4 + rr] += f0[rr] * v;                                          \
                    accC1[q * 4 + rr] += f1[rr] * v;                                          \
                    accC2[q * 4 + rr] += f2[rr] * v;                                          \
                }                                                                             \
            }                                                                                 \
        }                                                                                     \
    } while (0)

    short8 bA[8], bB[8], bC[8];
    float b2A, b2B, b2C;
    LOADB(0, bA, b2A); LOADB(1, bB, b2B); LOADB(2, bC, b2C);
    for (int p = 0; p < 60; p += 3) {
        COMPUTE(p,     bA, b2A); LOADB(p + 3, bA, b2A);
        COMPUTE(p + 1, bB, b2B); LOADB(p + 4, bB, b2B);
        COMPUTE(p + 2, bC, b2C); LOADB(p + 5, bC, b2C);
    }
    COMPUTE(60, bA, b2A); LOADB(63, bA, b2A);
    COMPUTE(61, bB, b2B);
    COMPUTE(62, bC, b2C);
    COMPUTE(63, bA, b2A);
#undef LOADB
#undef COMPUTE

    // epilogue: combine the two u-streams via LDS (red aliases Ctb)
    __syncthreads();
    if (ust == 1) {
#pragma unroll
        for (int q = 0; q < 4; ++q) {
#pragma unroll
            for (int rr = 0; rr < 4; ++rr) {
                int reg = q * 4 + rr;
                int el = esub * 32 + q * 8 + half * 4 + rr;
                int e = e0 + el; int ec = e < E ? e : E - 1;
                float4 sv = *(const float4*)(sh + (size_t)ec * 4);
                red[(((esub * 4 + 0) * 16 + reg) << 6) + lane] = acc0[reg];
                red[(((esub * 4 + 1) * 16 + reg) << 6) + lane] = sv.y * accB[reg] + accC0[reg];
                red[(((esub * 4 + 2) * 16 + reg) << 6) + lane] = sv.z * accB[reg] + accC1[reg];
                red[(((esub * 4 + 3) * 16 + reg) << 6) + lane] = sv.w * accB[reg] + accC2[reg];
            }
        }
    }
    __syncthreads();
    if (ust == 0) {
#pragma unroll
        for (int q = 0; q < 4; ++q) {
#pragma unroll
            for (int rr = 0; rr < 4; ++rr) {
                int reg = q * 4 + rr;
                int el = esub * 32 + q * 8 + half * 4 + rr;
                int e = e0 + el;
                if (e >= E) continue;
                float4 sv = *(const float4*)(sh + (size_t)e * 4);
                float a0 = acc0[reg] + red[(((esub * 4 + 0) * 16 + reg) << 6) + lane];
                float o0 = sv.y * accB[reg] + accC0[reg] + red[(((esub * 4 + 1) * 16 + reg) << 6) + lane];
                float o1 = sv.z * accB[reg] + accC1[reg] + red[(((esub * 4 + 2) * 16 + reg) << 6) + lane];
                float o2 = sv.w * accB[reg] + accC2[reg] + red[(((esub * 4 + 3) * 16 + reg) << 6) + lane];
                float* tpe = tp + (size_t)posbuf[el] * 128;   // CSR-ordered row
                tpe[col] = a0;
                tpe[32 + col * 3 + 0] = o0;
                tpe[32 + col * 3 + 1] = o1;
                tpe[32 + col * 3 + 2] = o2;
            }
        }
    }
}

// ---- K4: per-node gather-mean over CONTIGUOUS CSR-ordered tp rows ----
// tp rows for node n live at [rowptr[n], rowptr[n+1]) -> streaming scan,
// 4-wide unrolled (4 contiguous rows in flight). 1024 blocks (R9-verified).
__global__ __launch_bounds__(256) void k4_gather(const float* __restrict__ tp,
                                                 const int* __restrict__ rowptr,
                                                 const float* __restrict__ na,
                                                 float* __restrict__ pre,
                                                 float* __restrict__ stats, int N) {
    __shared__ float bns[96];
    const int tid = threadIdx.x;
    if (tid < 96) bns[tid] = 0.f;
    __syncthreads();
    const int o = tid & 127, hf = tid >> 7;
    for (int n = blockIdx.x * 2 + hf; n < N; n += gridDim.x * 2) {
        int r0 = rowptr[n], r1 = rowptr[n + 1];
        float s = 0.f;
        int j = r0;
        for (; j + 4 <= r1; j += 4) {
            float t0 = tp[(size_t)(j + 0) * 128 + o];
            float t1 = tp[(size_t)(j + 1) * 128 + o];
            float t2 = tp[(size_t)(j + 2) * 128 + o];
            float t3 = tp[(size_t)(j + 3) * 128 + o];
            s += (t0 + t1) + (t2 + t3);
        }
        for (; j < r1; ++j)
            s += tp[(size_t)j * 128 + o];
        int dg = r1 - r0;
        float cf = (float)(dg > 0 ? dg : 1);
        float v = s / cf + na[(size_t)n * 128 + o];
        pre[(size_t)n * 128 + o] = v;
        if (o < 32) {
            atomicAdd(&bns[o], v);
            atomicAdd(&bns[32 + o], v * v);
        } else {
            atomicAdd(&bns[64 + (o - 32) / 3], v * v);
        }
    }
    __syncthreads();
    if (tid < 96) atomicAdd(&stats[tid], bns[tid]);
}

// ---- K5: apply batch norm ----
__global__ __launch_bounds__(256) void k5_bn(const float* __restrict__ pre,
                                             const float* __restrict__ stats,
                                             const float* __restrict__ bnw,
                                             const float* __restrict__ bnb,
                                             float* __restrict__ out, int N) {
    size_t idx = (size_t)blockIdx.x * 256 + threadIdx.x;
    if (idx >= (size_t)N * 128) return;
    int o = (int)(idx & 127);
    float v = pre[idx];
    float invN = 1.f / (float)N;
    if (o < 32) {
        float m   = stats[o] * invN;
        float var = stats[32 + o] * invN - m * m;
        out[idx] = (v - m) * rsqrtf(var + EPSV) * bnw[o] + bnb[o];
    } else {
        int j = (o - 32) / 3;
        float vn = rsqrtf(stats[64 + j] * invN * (1.f / 3.f) + EPSV);
        out[idx] = v * vn * bnw[32 + j];
    }
}

extern "C" void kernel_launch(void* const* d_in, const int* in_sizes, int n_in,
                              void* d_out, int out_size, void* d_ws, size_t ws_size,
                              hipStream_t stream) {
    const float* node_attr  = (const float*)d_in[0];
    const int*   edge_index = (const int*)d_in[1];
    const float* edge_attr  = (const float*)d_in[2];
    const float* edge_sh    = (const float*)d_in[3];
    const float* W1  = (const float*)d_in[4];
    const float* b1  = (const float*)d_in[5];
    const float* W2  = (const float*)d_in[6];
    const float* b2  = (const float*)d_in[7];
    const float* bnw = (const float*)d_in[8];
    const float* bnb = (const float*)d_in[9];

    const int N = in_sizes[0] / 128;
    const int E = in_sizes[1] / 2;
    const int ngroups = ((E + 127) / 128) * 4;

    float* tp     = (float*)d_ws;                 // E*128 (CSR-ordered rows)
    float* pre    = tp + (size_t)E * 128;         // N*128
    float* stats  = pre + (size_t)N * 128;        // 96
    int*   deg    = (int*)(stats + 96);           // N
    int*   cursor = deg + N;                      // N
    int*   rowptr = cursor + N;                   // N+1
    char* pbase = (char*)(rowptr + N + 1);
    pbase += (16 - ((size_t)pbase & 15)) & 15;    // align 16
    unsigned short* hsw = (unsigned short*)pbase;          // ngroups*4096 bf16
    unsigned short* W2T = hsw + (size_t)ngroups * 4096;    // 524288
    unsigned short* W1T = W2T + (size_t)524288;            // 16384

    // zero stats+deg+cursor (contiguous) in one capture-safe memset
    hipMemsetAsync(stats, 0, (96 + 2 * (size_t)N) * sizeof(int), stream);

    k0_tile<<<132 + (E + 255) / 256, 256, 0, stream>>>(W2, W1, W2T, W1T,
                                                       edge_index, deg, E);
    k1_fc<<<(E + 127) / 128 + 1, 256, 0, stream>>>(edge_attr, W1T, b1, hsw,
                                                   deg, rowptr, N, E);
    k2_mfma<<<(E + 63) / 64, 256, 0, stream>>>(hsw, W2T, b2, node_attr, edge_index,
                                               edge_sh, rowptr, cursor, tp, E);
    k4_gather<<<1024, 256, 0, stream>>>(tp, rowptr, node_attr, pre, stats, N);
    size_t ntot = (size_t)N * 128;
    k5_bn<<<(int)((ntot + 255) / 256), 256, 0, stream>>>(pre, stats, bnw, bnb,
                                                         (float*)d_out, N);
}

// Round 15
// 254.162 us; speedup vs baseline: 1.1672x; 1.0006x over previous
//
#include <hip/hip_runtime.h>
#include <math.h>

#define EPSV 1e-5f
#define IS3  0.57735026918962576f   // 1/sqrt(3)
#define PNRM 0.125f                 // 1/sqrt(2*32)

typedef __attribute__((ext_vector_type(8)))  short  short8;
typedef __attribute__((ext_vector_type(16))) float  floatx16;

static __device__ inline unsigned short f2bf(float f) {
    unsigned int u = __float_as_uint(f);
    return (unsigned short)((u + 0x7fff + ((u >> 16) & 1)) >> 16);  // RNE
}
static __device__ inline float bflo(unsigned int u) { return __uint_as_float(u << 16); }
static __device__ inline float bfhi(unsigned int u) { return __uint_as_float(u & 0xffff0000u); }

// async global->LDS, 16B per lane; lds dest = uniform base + lane*16 (HW adds it)
#define GLD16(gp, lp) __builtin_amdgcn_global_load_lds( \
    (const __attribute__((address_space(1))) unsigned int*)(gp), \
    (__attribute__((address_space(3))) unsigned int*)(lp), 16, 0, 0)

// ---- K0: coalesced LDS-transpose f32 -> bf16 swizzled col-tiles, + deg count.
// blocks 0..127: W2 col-tiles; 128..131: W1 col-tiles; 132+: deg atomics
// tile layout (shorts): tile*4096 + kc*256 + (c&31)*8 + k7
__global__ __launch_bounds__(256) void k0_tile(const float* __restrict__ W2,
                                               const float* __restrict__ W1,
                                               unsigned short* __restrict__ W2T,
                                               unsigned short* __restrict__ W1T,
                                               const int* __restrict__ ei,
                                               int* __restrict__ deg, int E) {
    const int bx = blockIdx.x, tid = threadIdx.x;
    if (bx >= 132) {
        int e = (bx - 132) * 256 + tid;
        if (e < E) atomicAdd(&deg[ei[e]], 1);
        return;
    }
    __shared__ float tile[128 * 33];
    const float* src;
    unsigned short* dst;
    int nc, tb;
    if (bx < 128) { src = W2; dst = W2T; nc = 4096; tb = bx; }
    else          { src = W1; dst = W1T; nc = 128;  tb = bx - 128; }
    const int c0 = tb * 32;
#pragma unroll
    for (int r = 0; r < 16; ++r) {
        int lin = r * 256 + tid;
        int k = lin >> 5, c = lin & 31;
        tile[k * 33 + c] = src[(size_t)k * nc + c0 + c];
    }
    __syncthreads();
#pragma unroll
    for (int r = 0; r < 2; ++r) {
        int g = r * 256 + tid;          // 0..511
        int kc = g >> 5, c = g & 31;
        short8 v;
#pragma unroll
        for (int j = 0; j < 8; ++j)
            v[j] = (short)f2bf(tile[(kc * 8 + j) * 33 + c]);
        *(short8*)(dst + (size_t)tb * 4096 + kc * 256 + c * 8) = v;
    }
}

// ---- K1: h = relu(ea @ W1 + b1) via MFMA 32x32x16, PURE GEMM blocks,
// plus ONE extra block (last) doing the deg->rowptr exclusive scan.
// h layout: group g = e/32: short addr = g*4096 + (k>>3)*256 + (e&31)*8 + (k&7).
__global__ __launch_bounds__(256) void k1_fc(const float* __restrict__ ea,
                                             const unsigned short* __restrict__ W1T,
                                             const float* __restrict__ b1,
                                             unsigned short* __restrict__ hsw,
                                             const int* __restrict__ deg,
                                             int* __restrict__ rowptr,
                                             int N, int E) {
    __shared__ __align__(16) unsigned short W1s[16384];     // 32 KB swizzled tiles
    __shared__ __align__(16) unsigned short bounce[4 * 1056];  // 8.4 KB
    const int tid = threadIdx.x, lane = tid & 63, wv = tid >> 6;
    const int half = lane >> 5, col = lane & 31;
    const int nfc = (E + 127) / 128;

    if (blockIdx.x >= nfc) {
        // exclusive prefix sum deg -> rowptr (256 threads; LDS aliases W1s)
        int* part = (int*)W1s;
        const int chunk = (N + 255) / 256;
        const int base = tid * chunk;
        int s = 0;
        for (int i = 0; i < chunk; ++i) {
            int n = base + i;
            if (n < N) s += deg[n];
        }
        part[tid] = s;
        __syncthreads();
        for (int off = 1; off < 256; off <<= 1) {
            int t = 0;
            if (tid >= off) t = part[tid - off];
            __syncthreads();
            if (tid >= off) part[tid] += t;
            __syncthreads();
        }
        int prefix = (tid == 0) ? 0 : part[tid - 1];
        for (int i = 0; i < chunk; ++i) {
            int n = base + i;
            if (n < N) { rowptr[n] = prefix; prefix += deg[n]; }
        }
        if (tid == 0) rowptr[N] = part[255];
        return;
    }

    const int e0 = blockIdx.x * 128;

#pragma unroll
    for (int q = 0; q < 8; ++q) {
        int chunk = wv * 8 + q;
        GLD16((const char*)W1T + chunk * 1024 + lane * 16, (char*)W1s + chunk * 1024);
    }

    int e = e0 + wv * 32 + col; if (e >= E) e = E - 1;
    short8 afr[8];
#pragma unroll
    for (int c = 0; c < 8; ++c) {
        const float4* p = (const float4*)(ea + (size_t)e * 128 + c * 16 + half * 8);
        float4 f0 = p[0], f1 = p[1];
        short8 v;
        v[0] = (short)f2bf(f0.x); v[1] = (short)f2bf(f0.y);
        v[2] = (short)f2bf(f0.z); v[3] = (short)f2bf(f0.w);
        v[4] = (short)f2bf(f1.x); v[5] = (short)f2bf(f1.y);
        v[6] = (short)f2bf(f1.z); v[7] = (short)f2bf(f1.w);
        afr[c] = v;
    }
    __syncthreads();

    unsigned short* myb = bounce + wv * 1056;   // 4 chunks x 264 shorts
    const int gg = blockIdx.x * 4 + wv;
#pragma unroll
    for (int jt = 0; jt < 4; ++jt) {
        floatx16 d = {0,0,0,0,0,0,0,0,0,0,0,0,0,0,0,0};
#pragma unroll
        for (int c = 0; c < 8; ++c) {
            short8 bf = *(const short8*)((const char*)W1s + jt * 8192 + (2 * c + half) * 512 + col * 16);
            d = __builtin_amdgcn_mfma_f32_32x32x16_bf16(afr[c], bf, d, 0, 0, 0);
        }
        float b1v = b1[jt * 32 + col];
#pragma unroll
        for (int reg = 0; reg < 16; ++reg) {
            int r = (reg & 3) + 8 * (reg >> 2) + 4 * half;
            float v = d[reg] + b1v;
            v = v > 0.f ? v : 0.f;
            myb[(col >> 3) * 264 + r * 8 + (col & 7)] = f2bf(v);
        }
#pragma unroll
        for (int s = 0; s < 2; ++s) {
            short8 v = *(const short8*)&myb[(s * 2 + (lane >> 5)) * 264 + (lane & 31) * 8];
            *(short8*)(hsw + (size_t)gg * 4096 + jt * 1024 + s * 512 + lane * 8) = v;
        }
    }
}

// ---- K2: MFMA 32x32x16 GEMM (h @ W2) fused with TP contraction.
// EXACT R9 kernel (verified 110-120us): barrier-free hot loop, posbuf CSR
// slots, CSR-ordered tp row stores. DO NOT TOUCH.
__global__ __launch_bounds__(256, 2) void k2_mfma(const unsigned short* __restrict__ hsw,
                                                  const unsigned short* __restrict__ W2T,
                                                  const float* __restrict__ b2,
                                                  const float* __restrict__ na,
                                                  const int* __restrict__ ei,
                                                  const float* __restrict__ sh,
                                                  const int* __restrict__ rowptr,
                                                  int* __restrict__ cursor,
                                                  float* __restrict__ tp, int E) {
    __shared__ __align__(16) char smem[32768];
    __shared__ int posbuf[64];                     // edge -> CSR slot (this block)
    unsigned short* Ctb = (unsigned short*)smem;   // 6 x 4 KB coef tables
    float* red = (float*)smem;                     // 32 KB epilogue alias

    const int tid = threadIdx.x, lane = tid & 63, wv = tid >> 6;
    const int half = lane >> 5, col = lane & 31;
    const int ust = wv >> 1, esub = wv & 1;
    const int e0 = blockIdx.x * 64;

    // merged k_fill: claim CSR slots for this block's edges (no elist store)
    if (tid < 64) {
        int e = e0 + tid;
        if (e < E) {
            int s = ei[e];
            posbuf[tid] = rowptr[s] + atomicAdd(&cursor[s], 1);
        }
    }

    // coef tables (bf16), [u][el], pre-scaled by PNRM / PNRM*IS3 / s0
    for (int idx = tid; idx < 2048; idx += 256) {
        int el = idx & 63, u = idx >> 6;
        int e = e0 + el; int ec = e < E ? e : E - 1;
        int dn = ei[E + ec];
        const float* nar = na + (size_t)dn * 128;
        float x0  = nar[u];
        float x10 = nar[32 + u * 3], x11 = nar[33 + u * 3], x12 = nar[34 + u * 3];
        const float* shr = sh + (size_t)ec * 4;
        float s0 = shr[0], s1 = shr[1], s2 = shr[2], s3 = shr[3];
        int o = u * 64 + el;
        Ctb[0 * 2048 + o] = f2bf(PNRM * x0 * s0);
        Ctb[1 * 2048 + o] = f2bf(PNRM * IS3 * x0);
        Ctb[2 * 2048 + o] = f2bf(PNRM * IS3 * s0 * x10);
        Ctb[3 * 2048 + o] = f2bf(PNRM * IS3 * s0 * x11);
        Ctb[4 * 2048 + o] = f2bf(PNRM * IS3 * s0 * x12);
        Ctb[5 * 2048 + o] = f2bf(PNRM * IS3 * (x10 * s1 + x11 * s2 + x12 * s3));
    }

    // A fragments direct from swizzled h (coalesced 512B/half-wave)
    const int gg = blockIdx.x * 2 + esub;
    short8 afr[8];
#pragma unroll
    for (int c = 0; c < 8; ++c)
        afr[c] = *(const short8*)(hsw + (size_t)gg * 4096 + (2 * c + half) * 256 + col * 8);

    __syncthreads();

    float acc0[16] = {}, accB[16] = {}, accC0[16] = {}, accC1[16] = {}, accC2[16] = {};
    const int elb0 = esub * 32 + half * 4;
    const unsigned short* bbase = W2T + half * 256 + col * 8;

#define LOADB(p, br, b2r) do {                                         \
        int _ct = 2 * (p) + ust;                                       \
        const unsigned short* _bp = bbase + (size_t)_ct * 4096;        \
        _Pragma("unroll")                                              \
        for (int _c = 0; _c < 8; ++_c)                                 \
            (br)[_c] = *(const short8*)(_bp + _c * 512);               \
        (b2r) = b2[_ct * 32 + col];                                    \
    } while (0)

#define COMPUTE(p, br, b2v) do {                                                              \
        const int _ct = 2 * (p) + ust;                                                        \
        const int _b = _ct >> 5, _u = _ct & 31;                                               \
        floatx16 d = {0,0,0,0,0,0,0,0,0,0,0,0,0,0,0,0};                                       \
        _Pragma("unroll")                                                                     \
        for (int _c = 0; _c < 8; ++_c)                                                        \
            d = __builtin_amdgcn_mfma_f32_32x32x16_bf16(afr[_c], (br)[_c], d, 0, 0, 0);       \
        if (_b == 0 || _b == 3) {                                                             \
            const unsigned short* tb = Ctb + (_b == 0 ? 0 : 5) * 2048;                        \
            _Pragma("unroll")                                                                 \
            for (int q = 0; q < 4; ++q) {                                                     \
                uint2 cv = *(const uint2*)&tb[_u * 64 + elb0 + q * 8];                        \
                acc0[q * 4 + 0] += bflo(cv.x) * (d[q * 4 + 0] + (b2v));                       \
                acc0[q * 4 + 1] += bfhi(cv.x) * (d[q * 4 + 1] + (b2v));                       \
                acc0[q * 4 + 2] += bflo(cv.y) * (d[q * 4 + 2] + (b2v));                       \
                acc0[q * 4 + 3] += bfhi(cv.y) * (d[q * 4 + 3] + (b2v));                       \
            }                                                                                 \
        } else if (_b == 1) {                                                                 \
            _Pragma("unroll")                                                                 \
            for (int q = 0; q < 4; ++q) {                                                     \
                uint2 cv = *(const uint2*)&Ctb[1 * 2048 + _u * 64 + elb0 + q * 8];            \
                accB[q * 4 + 0] += bflo(cv.x) * (d[q * 4 + 0] + (b2v));                       \
                accB[q * 4 + 1] += bfhi(cv.x) * (d[q * 4 + 1] + (b2v));                       \
                accB[q * 4 + 2] += bflo(cv.y) * (d[q * 4 + 2] + (b2v));                       \
                accB[q * 4 + 3] += bfhi(cv.y) * (d[q * 4 + 3] + (b2v));                       \
            }                                                                                 \
        } else {                                                                              \
            _Pragma("unroll")                                                                 \
            for (int q = 0; q < 4; ++q) {                                                     \
                uint2 cu0 = *(const uint2*)&Ctb[2 * 2048 + _u * 64 + elb0 + q * 8];           \
                uint2 cu1 = *(const uint2*)&Ctb[3 * 2048 + _u * 64 + elb0 + q * 8];           \
                uint2 cu2 = *(const uint2*)&Ctb[4 * 2048 + _u * 64 + elb0 + q * 8];           \
                float f0[4] = {bflo(cu0.x), bfhi(cu0.x), bflo(cu0.y), bfhi(cu0.y)};           \
                float f1[4] = {bflo(cu1.x), bfhi(cu1.x), bflo(cu1.y), bfhi(cu1.y)};           \
                float f2[4] = {bflo(cu2.x), bfhi(cu2.x), bflo(cu2.y), bfhi(cu2.y)};           \
                _Pragma("unroll")                                                             \
                for (int rr = 0; rr < 4; ++rr) {                                              \
                    float v = d[q * 4 + rr] + (b2v);                                          \
                    accC0[q * 4 + rr] += f0[rr] * v;                                          \
                    accC1[q * 4 + rr] += f1[rr] * v;                                          \
                    accC2[q * 4 + rr] += f2[rr] * v;                                          \
                }                                                                             \
            }                                                                                 \
        }                                                                                     \
    } while (0)

    short8 bA[8], bB[8], bC[8];
    float b2A, b2B, b2C;
    LOADB(0, bA, b2A); LOADB(1, bB, b2B); LOADB(2, bC, b2C);
    for (int p = 0; p < 60; p += 3) {
        COMPUTE(p,     bA, b2A); LOADB(p + 3, bA, b2A);
        COMPUTE(p + 1, bB, b2B); LOADB(p + 4, bB, b2B);
        COMPUTE(p + 2, bC, b2C); LOADB(p + 5, bC, b2C);
    }
    COMPUTE(60, bA, b2A); LOADB(63, bA, b2A);
    COMPUTE(61, bB, b2B);
    COMPUTE(62, bC, b2C);
    COMPUTE(63, bA, b2A);
#undef LOADB
#undef COMPUTE

    // epilogue: combine the two u-streams via LDS (red aliases Ctb)
    __syncthreads();
    if (ust == 1) {
#pragma unroll
        for (int q = 0; q < 4; ++q) {
#pragma unroll
            for (int rr = 0; rr < 4; ++rr) {
                int reg = q * 4 + rr;
                int el = esub * 32 + q * 8 + half * 4 + rr;
                int e = e0 + el; int ec = e < E ? e : E - 1;
                float4 sv = *(const float4*)(sh + (size_t)ec * 4);
                red[(((esub * 4 + 0) * 16 + reg) << 6) + lane] = acc0[reg];
                red[(((esub * 4 + 1) * 16 + reg) << 6) + lane] = sv.y * accB[reg] + accC0[reg];
                red[(((esub * 4 + 2) * 16 + reg) << 6) + lane] = sv.z * accB[reg] + accC1[reg];
                red[(((esub * 4 + 3) * 16 + reg) << 6) + lane] = sv.w * accB[reg] + accC2[reg];
            }
        }
    }
    __syncthreads();
    if (ust == 0) {
#pragma unroll
        for (int q = 0; q < 4; ++q) {
#pragma unroll
            for (int rr = 0; rr < 4; ++rr) {
                int reg = q * 4 + rr;
                int el = esub * 32 + q * 8 + half * 4 + rr;
                int e = e0 + el;
                if (e >= E) continue;
                float4 sv = *(const float4*)(sh + (size_t)e * 4);
                float a0 = acc0[reg] + red[(((esub * 4 + 0) * 16 + reg) << 6) + lane];
                float o0 = sv.y * accB[reg] + accC0[reg] + red[(((esub * 4 + 1) * 16 + reg) << 6) + lane];
                float o1 = sv.z * accB[reg] + accC1[reg] + red[(((esub * 4 + 2) * 16 + reg) << 6) + lane];
                float o2 = sv.w * accB[reg] + accC2[reg] + red[(((esub * 4 + 3) * 16 + reg) << 6) + lane];
                float* tpe = tp + (size_t)posbuf[el] * 128;   // CSR-ordered row
                tpe[col] = a0;
                tpe[32 + col * 3 + 0] = o0;
                tpe[32 + col * 3 + 1] = o1;
                tpe[32 + col * 3 + 2] = o2;
            }
        }
    }
}

// ---- K4: per-node gather-mean over CONTIGUOUS CSR-ordered tp rows ----
// tp rows for node n live at [rowptr[n], rowptr[n+1]) -> streaming scan,
// 4-wide unrolled (4 contiguous rows in flight). 1024 blocks (R9-verified).
__global__ __launch_bounds__(256) void k4_gather(const float* __restrict__ tp,
                                                 const int* __restrict__ rowptr,
                                                 const float* __restrict__ na,
                                                 float* __restrict__ pre,
                                                 float* __restrict__ stats, int N) {
    __shared__ float bns[96];
    const int tid = threadIdx.x;
    if (tid < 96) bns[tid] = 0.f;
    __syncthreads();
    const int o = tid & 127, hf = tid >> 7;
    for (int n = blockIdx.x * 2 + hf; n < N; n += gridDim.x * 2) {
        int r0 = rowptr[n], r1 = rowptr[n + 1];
        float s = 0.f;
        int j = r0;
        for (; j + 4 <= r1; j += 4) {
            float t0 = tp[(size_t)(j + 0) * 128 + o];
            float t1 = tp[(size_t)(j + 1) * 128 + o];
            float t2 = tp[(size_t)(j + 2) * 128 + o];
            float t3 = tp[(size_t)(j + 3) * 128 + o];
            s += (t0 + t1) + (t2 + t3);
        }
        for (; j < r1; ++j)
            s += tp[(size_t)j * 128 + o];
        int dg = r1 - r0;
        float cf = (float)(dg > 0 ? dg : 1);
        float v = s / cf + na[(size_t)n * 128 + o];
        pre[(size_t)n * 128 + o] = v;
        if (o < 32) {
            atomicAdd(&bns[o], v);
            atomicAdd(&bns[32 + o], v * v);
        } else {
            atomicAdd(&bns[64 + (o - 32) / 3], v * v);
        }
    }
    __syncthreads();
    if (tid < 96) atomicAdd(&stats[tid], bns[tid]);
}

// ---- K5: apply batch norm — vectorized (float4, 4 elems/thread).
// Per-block: precompute the 128 per-feature (scale,bias) pairs into LDS
// (one rsqrtf per feature per block, not per element), then a branch-free
// float4 main path: 16B/lane loads+stores (was 4B scalar).
__global__ __launch_bounds__(256) void k5_bn(const float* __restrict__ pre,
                                             const float* __restrict__ stats,
                                             const float* __restrict__ bnw,
                                             const float* __restrict__ bnb,
                                             float* __restrict__ out, int N) {
    __shared__ float sc[128], bi[128];
    const int tid = threadIdx.x;
    if (tid < 128) {
        int o = tid;
        float invN = 1.f / (float)N;
        if (o < 32) {
            float m   = stats[o] * invN;
            float var = stats[32 + o] * invN - m * m;
            float is  = rsqrtf(var + EPSV) * bnw[o];
            sc[o] = is; bi[o] = bnb[o] - m * is;
        } else {
            int j = (o - 32) / 3;
            sc[o] = rsqrtf(stats[64 + j] * invN * (1.f / 3.f) + EPSV) * bnw[32 + j];
            bi[o] = 0.f;
        }
    }
    __syncthreads();
    size_t i4 = ((size_t)blockIdx.x * 256 + tid) * 4;
    if (i4 >= (size_t)N * 128) return;
    float4 v = *(const float4*)(pre + i4);
    int o = (int)(i4 & 127);        // multiple of 4; o+3 <= 127
    float4 r;
    r.x = v.x * sc[o + 0] + bi[o + 0];
    r.y = v.y * sc[o + 1] + bi[o + 1];
    r.z = v.z * sc[o + 2] + bi[o + 2];
    r.w = v.w * sc[o + 3] + bi[o + 3];
    *(float4*)(out + i4) = r;
}

extern "C" void kernel_launch(void* const* d_in, const int* in_sizes, int n_in,
                              void* d_out, int out_size, void* d_ws, size_t ws_size,
                              hipStream_t stream) {
    const float* node_attr  = (const float*)d_in[0];
    const int*   edge_index = (const int*)d_in[1];
    const float* edge_attr  = (const float*)d_in[2];
    const float* edge_sh    = (const float*)d_in[3];
    const float* W1  = (const float*)d_in[4];
    const float* b1  = (const float*)d_in[5];
    const float* W2  = (const float*)d_in[6];
    const float* b2  = (const float*)d_in[7];
    const float* bnw = (const float*)d_in[8];
    const float* bnb = (const float*)d_in[9];

    const int N = in_sizes[0] / 128;
    const int E = in_sizes[1] / 2;
    const int ngroups = ((E + 127) / 128) * 4;

    float* tp     = (float*)d_ws;                 // E*128 (CSR-ordered rows)
    float* pre    = tp + (size_t)E * 128;         // N*128
    float* stats  = pre + (size_t)N * 128;        // 96
    int*   deg    = (int*)(stats + 96);           // N
    int*   cursor = deg + N;                      // N
    int*   rowptr = cursor + N;                   // N+1
    char* pbase = (char*)(rowptr + N + 1);
    pbase += (16 - ((size_t)pbase & 15)) & 15;    // align 16
    unsigned short* hsw = (unsigned short*)pbase;          // ngroups*4096 bf16
    unsigned short* W2T = hsw + (size_t)ngroups * 4096;    // 524288
    unsigned short* W1T = W2T + (size_t)524288;            // 16384

    // zero stats+deg+cursor (contiguous) in one capture-safe memset
    hipMemsetAsync(stats, 0, (96 + 2 * (size_t)N) * sizeof(int), stream);

    k0_tile<<<132 + (E + 255) / 256, 256, 0, stream>>>(W2, W1, W2T, W1T,
                                                       edge_index, deg, E);
    k1_fc<<<(E + 127) / 128 + 1, 256, 0, stream>>>(edge_attr, W1T, b1, hsw,
                                                   deg, rowptr, N, E);
    k2_mfma<<<(E + 63) / 64, 256, 0, stream>>>(hsw, W2T, b2, node_attr, edge_index,
                                               edge_sh, rowptr, cursor, tp, E);
    k4_gather<<<1024, 256, 0, stream>>>(tp, rowptr, node_attr, pre, stats, N);
    size_t ntot4 = ((size_t)N * 128) / 4;
    k5_bn<<<(int)((ntot4 + 255) / 256), 256, 0, stream>>>(pre, stats, bnw, bnb,
                                                          (float*)d_out, N);
}